// Round 8
// baseline (601.073 us; speedup 1.0000x reference)
//
#include <hip/hip_runtime.h>

#define VOCAB_ROWS 50001
#define EMB 32
#define UNITS 16
#define GATES 48
#define BATCH 256
#define SEQ 4096

// -log2(e): all gate pre-activations prescaled so sigmoid(t) = rcp(1+exp2(v)).
#define NEGLOG2E (-1.4426950408889634f)

#if __has_builtin(__builtin_amdgcn_exp2f)
#define EXP2F(x) __builtin_amdgcn_exp2f(x)
#else
#define EXP2F(x) exp2f(x)
#endif

// ---------------- Phase 1: per-vocab projection table (prescaled) ----------
// v2: thread-per-vocab-row. 48 accumulators; kern/bias reads are uniform
// (scalarize to s_load); emb row = 8 float4; stores = 12 float4. ~16 instrs
// per output byte-group vs 73/dword for the old thread-per-element mapping.
__global__ __launch_bounds__(256) void proj_kernel(const float* __restrict__ emb,
                                                   const float* __restrict__ kern,
                                                   const float* __restrict__ bias,
                                                   float* __restrict__ proj) {
    int v = blockIdx.x * 256 + threadIdx.x;
    if (v >= VOCAB_ROWS) return;

    float4 ev[EMB / 4];
    const float4* e4 = (const float4*)(emb + (size_t)v * EMB);
#pragma unroll
    for (int i = 0; i < EMB / 4; ++i) ev[i] = e4[i];

    float acc[GATES];
#pragma unroll
    for (int jj = 0; jj < GATES; ++jj) acc[jj] = bias[jj];   // uniform -> s_load

#pragma unroll
    for (int k = 0; k < EMB; ++k) {
        const float ek = ((const float*)ev)[k];              // static index
        const float* kr = kern + k * GATES;                  // uniform row
#pragma unroll
        for (int jj = 0; jj < GATES; ++jj)
            acc[jj] = fmaf(ek, kr[jj], acc[jj]);             // uniform kern -> s_load
    }

    float4* o4 = (float4*)(proj + (size_t)v * GATES);        // 192B row, 16B-aligned
#pragma unroll
    for (int q = 0; q < GATES / 4; ++q) {
        float4 w;
        w.x = acc[4 * q + 0] * NEGLOG2E;
        w.y = acc[4 * q + 1] * NEGLOG2E;
        w.z = acc[4 * q + 2] * NEGLOG2E;
        w.w = acc[4 * q + 3] * NEGLOG2E;
        o4[q] = w;
    }
}

// ---------------- Phase 2: sequential GRU scan ----------------
__device__ __forceinline__ float rdlane(float v, int l) {
    return __int_as_float(__builtin_amdgcn_readlane(__float_as_int(v), l));
}

// gfx950 VALU cross-lane half-swaps via builtins (R5/R6/R7-verified correct).
typedef unsigned u32x2 __attribute__((ext_vector_type(2)));

template <bool SB>
__device__ __forceinline__ float swap32t(float y) {
    u32x2 r = __builtin_amdgcn_permlane32_swap(__float_as_uint(y), __float_as_uint(y),
                                               false, false);
    return __uint_as_float(SB ? r[1] : r[0]);
}
template <bool SB>
__device__ __forceinline__ float swap16t(float y) {
    u32x2 r = __builtin_amdgcn_permlane16_swap(__float_as_uint(y), __float_as_uint(y),
                                               false, false);
    return __uint_as_float(SB ? r[1] : r[0]);
}

// One GRU step -- arithmetic bit-identical to the R7 passing body (same
// association); only change: all 16 h-broadcasts batched BEFORE the FMA
// block so the readlane->SGPR writes pipeline instead of interleaving with
// their consumers (VALU-write->SGPR-read wait states).
#define GRU_STEP(XV) do {                                              \
    const float x_ = (XV);                                             \
    float hb_[16];                                                     \
    _Pragma("unroll")                                                  \
    for (int k = 0; k < 16; ++k) hb_[k] = rdlane(h, k);                \
    float a0 = bj, a1 = 0.f, a2 = 0.f, a3 = 0.f;                       \
    _Pragma("unroll")                                                  \
    for (int k = 0; k < 4; ++k) {                                      \
        a0 = fmaf(R[k],      hb_[k],      a0);                         \
        a1 = fmaf(R[k + 4],  hb_[k + 4],  a1);                         \
        a2 = fmaf(R[k + 8],  hb_[k + 8],  a2);                         \
        a3 = fmaf(R[k + 12], hb_[k + 12], a3);                         \
    }                                                                  \
    const float a_ = (a0 + a1) + (a2 + a3);                            \
    const float y_ = __builtin_amdgcn_rcpf(1.0f + EXP2F(x_ + a_));     \
    const float rt = swap16t<SB16>(y_);                                \
    const float at = swap32t<SB32>(a_);                                \
    const float xt = swap32t<SB32>(x_);                                \
    const float p_ = y_ * h;                                           \
    const float q_ = 1.0f - y_;                                        \
    const float hh = __builtin_amdgcn_rcpf(1.0f + EXP2F(fmaf(rt, at, xt))); \
    h = fmaf(q_, hh, p_);                                              \
} while (0)

// Load 8 wave-uniform ids (2 int4 at uniform address -> one coalesced line;
// clamped so the last row's dead prefetches stay in-bounds).
#define LOADIDS(P0, P1, BASE) do {                                     \
    int bb_ = (BASE);                                                  \
    bb_ = bb_ <= SEQ - 8 ? bb_ : SEQ - 8;                              \
    const int4* ip_ = (const int4*)(idrow + bb_);                      \
    P0 = ip_[0]; P1 = ip_[1];                                          \
} while (0)

// Clustered 8-wide gather. Ids were loaded one phase earlier (vmcnt long
// retired -> counted wait, no stall). readfirstlane -> SGPR row base; the
// per-lane j offset is a loop-invariant VGPR => global_load v, v_j, s[base]
// with ZERO per-gather VALU address math (all on the SALU pipe).
#define GATHER(BUF, P0, P1) do {                                       \
    const float* r0_ = proj + (size_t)(unsigned)__builtin_amdgcn_readfirstlane(P0.x) * GATES; \
    const float* r1_ = proj + (size_t)(unsigned)__builtin_amdgcn_readfirstlane(P0.y) * GATES; \
    const float* r2_ = proj + (size_t)(unsigned)__builtin_amdgcn_readfirstlane(P0.z) * GATES; \
    const float* r3_ = proj + (size_t)(unsigned)__builtin_amdgcn_readfirstlane(P0.w) * GATES; \
    const float* r4_ = proj + (size_t)(unsigned)__builtin_amdgcn_readfirstlane(P1.x) * GATES; \
    const float* r5_ = proj + (size_t)(unsigned)__builtin_amdgcn_readfirstlane(P1.y) * GATES; \
    const float* r6_ = proj + (size_t)(unsigned)__builtin_amdgcn_readfirstlane(P1.z) * GATES; \
    const float* r7_ = proj + (size_t)(unsigned)__builtin_amdgcn_readfirstlane(P1.w) * GATES; \
    BUF[0] = r0_[j]; BUF[1] = r1_[j]; BUF[2] = r2_[j]; BUF[3] = r3_[j]; \
    BUF[4] = r4_[j]; BUF[5] = r5_[j]; BUF[6] = r6_[j]; BUF[7] = r7_[j]; \
} while (0)

// Column-per-lane layout: lane j in [0,48) owns gate column j of the 16x48
// matvec (z: 0-15, r: 16-31, h: 32-47); lanes 48-63 mirror 32-47.
// h state lives in lanes 0-15. No LDS. Double-buffered clustered gathers
// (R6-verified); ids prefetched one phase ahead into registers.
template <bool SB32, bool SB16>
__device__ __forceinline__ void scan_body(const int* __restrict__ idrow,
                                          const float* __restrict__ reck,
                                          const float* __restrict__ bias,
                                          const float* __restrict__ proj,
                                          float* __restrict__ out,
                                          int lane, int j, int b) {
    float R[UNITS];
#pragma unroll
    for (int k = 0; k < UNITS; ++k) R[k] = reck[k * GATES + j] * NEGLOG2E;
    const float bj = bias[GATES + j] * NEGLOG2E;

    int4 ia0, ia1, ib0, ib1;
    float xa[8], xb[8];
    LOADIDS(ia0, ia1, 0);
    LOADIDS(ib0, ib1, 8);
    GATHER(xa, ia0, ia1);                  // steps 0..7
    GATHER(xb, ib0, ib1);                  // steps 8..15
    LOADIDS(ia0, ia1, 16);                 // ids for steps 16..23
    LOADIDS(ib0, ib1, 24);                 // ids for steps 24..31

    float h = 0.0f;                        // valid in lanes 0-15
    for (int t0 = 0; t0 < SEQ; t0 += 16) {
#pragma unroll
        for (int uu = 0; uu < 8; ++uu) GRU_STEP(xa[uu]);
        GATHER(xa, ia0, ia1);              // proj rows for steps t0+16..t0+23
        LOADIDS(ia0, ia1, t0 + 32);        // ids for steps t0+32.. (next iter)
#pragma unroll
        for (int uu = 0; uu < 8; ++uu) GRU_STEP(xb[uu]);
        GATHER(xb, ib0, ib1);              // steps t0+24..t0+31
        LOADIDS(ib0, ib1, t0 + 40);
    }

    if (lane < UNITS) out[b * UNITS + lane] = h;
}

__global__ __launch_bounds__(64, 1) void gru_scan(const int* __restrict__ ids,
                                                  const float* __restrict__ reck,
                                                  const float* __restrict__ bias,
                                                  const float* __restrict__ proj,
                                                  float* __restrict__ out) {
    const int lane = threadIdx.x & 63;
    const int j    = (lane < 48) ? lane : lane - 16;   // owned gate column
    const int b    = blockIdx.x;                       // one batch row per wave
    const int* __restrict__ idrow = ids + (size_t)b * SEQ;

    // probe swap output-order once (wave-uniform), then run fully specialized
    bool selB32, selB16;
    {
        unsigned li = __float_as_uint((float)lane);
        u32x2 p32 = __builtin_amdgcn_permlane32_swap(li, li, false, false);
        selB32 = (rdlane(__uint_as_float(p32[1]), 0) == 32.0f);
        u32x2 p16 = __builtin_amdgcn_permlane16_swap(li, li, false, false);
        selB16 = (rdlane(__uint_as_float(p16[1]), 0) == 16.0f);
    }

    if (selB32) {
        if (selB16) scan_body<true,  true >(idrow, reck, bias, proj, out, lane, j, b);
        else        scan_body<true,  false>(idrow, reck, bias, proj, out, lane, j, b);
    } else {
        if (selB16) scan_body<false, true >(idrow, reck, bias, proj, out, lane, j, b);
        else        scan_body<false, false>(idrow, reck, bias, proj, out, lane, j, b);
    }
}

extern "C" void kernel_launch(void* const* d_in, const int* in_sizes, int n_in,
                              void* d_out, int out_size, void* d_ws, size_t ws_size,
                              hipStream_t stream) {
    const int*   ids  = (const int*)d_in[0];
    const float* emb  = (const float*)d_in[1];
    const float* kern = (const float*)d_in[2];
    const float* reck = (const float*)d_in[3];
    const float* bias = (const float*)d_in[4];
    float* out  = (float*)d_out;
    float* proj = (float*)d_ws;   // 50001*48 floats = 9.6 MB scratch

    proj_kernel<<<(VOCAB_ROWS + 255) / 256, 256, 0, stream>>>(emb, kern, bias, proj);
    gru_scan<<<BATCH, 64, 0, stream>>>(ids, reck, bias, proj, out);
}